// Round 1
// baseline (3680.088 us; speedup 1.0000x reference)
//
#include <hip/hip_runtime.h>
#include <math.h>

// Problem: N=16384 rows, D=2048 in-features, O=2048 out-features, all fp32.
// out = clamp_small(catx@w1^T + b1) is WRONG ordering note: reference clamps h1
// and sigmoid(h2) separately, then multiplies. catx = (x-mean)*rsqrt(var_unbiased+1e-8)*gamma+beta.

#define BN_EPS 1e-8f
#define CLAMP_EPS 1e-12f

__device__ __forceinline__ float clamp_small(float t) {
    if (t >= 0.0f && t < CLAMP_EPS) t = CLAMP_EPS;
    else if (t < 0.0f && t > -CLAMP_EPS) t = -CLAMP_EPS;
    return t;
}

// ---------------- stats: per-column mean / unbiased var ----------------
// grid (D/256, RB). Each block: 256 columns x (N/RB) rows partial sums.
// Deterministic (no atomics): partials written to ws, reduced in finalize.
__global__ __launch_bounds__(256) void stats_partial(
    const float* __restrict__ x, float* __restrict__ psum, float* __restrict__ psq,
    int N, int D, int rows_per_block)
{
    int col = blockIdx.x * 256 + threadIdx.x;
    int r0 = blockIdx.y * rows_per_block;
    const float* p = x + (size_t)r0 * D + col;
    float s = 0.0f, q = 0.0f;
    for (int r = 0; r < rows_per_block; ++r) {
        float v = p[(size_t)r * D];
        s += v;
        q += v * v;
    }
    psum[(size_t)blockIdx.y * D + col] = s;
    psq [(size_t)blockIdx.y * D + col] = q;
}

__global__ __launch_bounds__(256) void stats_finalize(
    const float* __restrict__ psum, const float* __restrict__ psq,
    const float* __restrict__ gamma, const float* __restrict__ beta,
    float* __restrict__ scale, float* __restrict__ shift,
    int D, int nparts, float n)
{
    int col = blockIdx.x * 256 + threadIdx.x;
    if (col >= D) return;
    float s = 0.0f, q = 0.0f;
    for (int i = 0; i < nparts; ++i) {
        s += psum[(size_t)i * D + col];
        q += psq [(size_t)i * D + col];
    }
    float mean = s / n;
    // unbiased variance (torch.std ddof=1): (sum(x^2) - n*mean^2)/(n-1)
    float var = (q - n * mean * mean) / (n - 1.0f);
    float vs = rsqrtf(var + BN_EPS);
    float sc = gamma[col] * vs;
    scale[col] = sc;
    shift[col] = beta[col] - mean * sc;
}

// ---------------- fused dual GEMM + epilogue ----------------
// out[n][o] = clamp(sum_k catx[n][k]*w1[o][k] + b1[o]) * clamp(sigmoid(sum_k catx[n][k]*w2[o][k] + b2[o]))
// catx[n][k] = x[n][k]*scale[k] + shift[k], folded into A staging.
// Tiles: BM=128, BN=64, BK=16. 256 threads = (ty 0..15) x (tx 0..15).
// Per thread: 8 rows x 4 cols, two accumulator sets.
constexpr int BM = 128, BN = 64, BK = 16;
constexpr int APAD = BM + 4;  // 132: staging write ~2-way, b128-aligned rows
constexpr int BPAD = BN + 4;  // 68

__global__ __launch_bounds__(256) void dual_gemm(
    const float* __restrict__ x,
    const float* __restrict__ w1, const float* __restrict__ b1,
    const float* __restrict__ w2, const float* __restrict__ b2,
    const float* __restrict__ scale, const float* __restrict__ shift,
    float* __restrict__ out, int N, int D, int O)
{
    __shared__ float As [BK][APAD];
    __shared__ float Bs1[BK][BPAD];
    __shared__ float Bs2[BK][BPAD];

    const int tid = threadIdx.x;
    const int ty = tid >> 4;        // 0..15 -> 8 rows each
    const int tx = tid & 15;        // 0..15 -> 4 cols each
    const int bm = blockIdx.x * BM;
    const int bn = blockIdx.y * BN;

    float acc1[8][4] = {};
    float acc2[8][4] = {};

    for (int k0 = 0; k0 < D; k0 += BK) {
        // stage A: BM*BK = 2048 elems, 8 per thread, normalize on the fly
        #pragma unroll
        for (int i = 0; i < 8; ++i) {
            int e = tid + i * 256;
            int row = e >> 4;       // 0..127
            int kk = e & 15;
            float v = x[(size_t)(bm + row) * D + (k0 + kk)];
            As[kk][row] = fmaf(v, scale[k0 + kk], shift[k0 + kk]);
        }
        // stage B1/B2: BN*BK = 1024 elems each, 4 per thread
        #pragma unroll
        for (int i = 0; i < 4; ++i) {
            int e = tid + i * 256;
            int o = e >> 4;         // 0..63
            int kk = e & 15;
            Bs1[kk][o] = w1[(size_t)(bn + o) * D + (k0 + kk)];
            Bs2[kk][o] = w2[(size_t)(bn + o) * D + (k0 + kk)];
        }
        __syncthreads();

        #pragma unroll
        for (int kk = 0; kk < BK; ++kk) {
            float a[8], v1[4], v2[4];
            #pragma unroll
            for (int i = 0; i < 8; ++i) a[i] = As[kk][ty * 8 + i];
            #pragma unroll
            for (int j = 0; j < 4; ++j) { v1[j] = Bs1[kk][tx * 4 + j]; v2[j] = Bs2[kk][tx * 4 + j]; }
            #pragma unroll
            for (int i = 0; i < 8; ++i)
                #pragma unroll
                for (int j = 0; j < 4; ++j) {
                    acc1[i][j] = fmaf(a[i], v1[j], acc1[i][j]);
                    acc2[i][j] = fmaf(a[i], v2[j], acc2[i][j]);
                }
        }
        __syncthreads();
    }

    // epilogue
    float bias1[4], bias2[4];
    #pragma unroll
    for (int j = 0; j < 4; ++j) {
        bias1[j] = b1[bn + tx * 4 + j];
        bias2[j] = b2[bn + tx * 4 + j];
    }
    #pragma unroll
    for (int i = 0; i < 8; ++i) {
        #pragma unroll
        for (int j = 0; j < 4; ++j) {
            float h1 = acc1[i][j] + bias1[j];
            float h2 = acc2[i][j] + bias2[j];
            float sg = 1.0f / (1.0f + expf(-h2));
            h1 = clamp_small(h1);
            sg = clamp_small(sg);
            out[(size_t)(bm + ty * 8 + i) * O + (bn + tx * 4 + j)] = h1 * sg;
        }
    }
}

extern "C" void kernel_launch(void* const* d_in, const int* in_sizes, int n_in,
                              void* d_out, int out_size, void* d_ws, size_t ws_size,
                              hipStream_t stream)
{
    const float* x     = (const float*)d_in[0];
    const float* w1    = (const float*)d_in[1];
    const float* b1    = (const float*)d_in[2];
    const float* w2    = (const float*)d_in[3];
    const float* b2    = (const float*)d_in[4];
    const float* gamma = (const float*)d_in[5];
    const float* beta  = (const float*)d_in[6];
    float* out = (float*)d_out;

    const int D = in_sizes[5];            // 2048 (gamma)
    const int O = in_sizes[2];            // 2048 (b1)
    const int N = in_sizes[0] / D;        // 16384

    const int RB = 64;                    // row partials
    float* psum  = (float*)d_ws;                     // [RB][D]
    float* psq   = psum + (size_t)RB * D;            // [RB][D]
    float* scale = psq  + (size_t)RB * D;            // [D]
    float* shift = scale + D;                        // [D]

    stats_partial<<<dim3(D / 256, RB), 256, 0, stream>>>(x, psum, psq, N, D, N / RB);
    stats_finalize<<<(D + 255) / 256, 256, 0, stream>>>(psum, psq, gamma, beta, scale, shift, D, RB, (float)N);
    dual_gemm<<<dim3(N / BM, O / BN), 256, 0, stream>>>(x, w1, b1, w2, b2, scale, shift, out, N, D, O);
}

// Round 2
// 1210.241 us; speedup vs baseline: 3.0408x; 3.0408x over previous
//
#include <hip/hip_runtime.h>
#include <hip/hip_bf16.h>
#include <math.h>

// R2: bf16x3 split-precision MFMA dual-GEMM.
// out = clamp(catx@w1^T+b1) * clamp(sigmoid(catx@w2^T+b2))
// catx = x*scale + shift, scale=gamma*rsqrt(var_ddof1+1e-8), shift=beta-mean*scale.
// catx and w are each split hi+lo bf16; product via 3 bf16 MFMA terms (hi*hi, hi*lo, lo*hi).
// Requires ~161MB workspace; falls back to R1 fp32 kernel if ws too small.

#define BN_EPS 1e-8f
#define CLAMP_EPS 1e-12f

typedef __attribute__((ext_vector_type(8))) __bf16 bf16x8;
typedef __attribute__((ext_vector_type(4))) float f32x4;
typedef __attribute__((ext_vector_type(4))) unsigned short ushort4v;
typedef __attribute__((ext_vector_type(4))) float float4v;

__device__ __forceinline__ float clamp_small(float t) {
    if (t >= 0.0f && t < CLAMP_EPS) t = CLAMP_EPS;
    else if (t < 0.0f && t > -CLAMP_EPS) t = -CLAMP_EPS;
    return t;
}

__device__ __forceinline__ unsigned short f2bf(float v) {
    __hip_bfloat16 b = __float2bfloat16(v);  // RNE
    return __builtin_bit_cast(unsigned short, b);
}
__device__ __forceinline__ float bfbits2f(unsigned short u) {
    unsigned int x = ((unsigned int)u) << 16;
    return __builtin_bit_cast(float, x);
}

// async 16B global->LDS (wave-uniform dest base + lane*16; LDS layout must be linear in lane order)
#define GL16(g, l)                                                              \
    __builtin_amdgcn_global_load_lds(                                           \
        (const __attribute__((address_space(1))) void*)(g),                     \
        (__attribute__((address_space(3))) void*)(l), 16, 0, 0)

#define MFMA(a, b, c) __builtin_amdgcn_mfma_f32_16x16x32_bf16((a), (b), (c), 0, 0, 0)

// ---------------- stats (unchanged from R1, measured cheap) ----------------
__global__ __launch_bounds__(256) void stats_partial(
    const float* __restrict__ x, float* __restrict__ psum, float* __restrict__ psq,
    int N, int D, int rows_per_block)
{
    int col = blockIdx.x * 256 + threadIdx.x;
    int r0 = blockIdx.y * rows_per_block;
    const float* p = x + (size_t)r0 * D + col;
    float s = 0.0f, q = 0.0f;
    for (int r = 0; r < rows_per_block; ++r) {
        float v = p[(size_t)r * D];
        s += v;
        q += v * v;
    }
    psum[(size_t)blockIdx.y * D + col] = s;
    psq [(size_t)blockIdx.y * D + col] = q;
}

__global__ __launch_bounds__(256) void stats_finalize(
    const float* __restrict__ psum, const float* __restrict__ psq,
    const float* __restrict__ gamma, const float* __restrict__ beta,
    float* __restrict__ scale, float* __restrict__ shift,
    int D, int nparts, float n)
{
    int col = blockIdx.x * 256 + threadIdx.x;
    if (col >= D) return;
    float s = 0.0f, q = 0.0f;
    for (int i = 0; i < nparts; ++i) {
        s += psum[(size_t)i * D + col];
        q += psq [(size_t)i * D + col];
    }
    float mean = s / n;
    float var = (q - n * mean * mean) / (n - 1.0f);  // ddof=1
    float vs = rsqrtf(var + BN_EPS);
    float sc = gamma[col] * vs;
    scale[col] = sc;
    shift[col] = beta[col] - mean * sc;
}

// ---------------- split transforms ----------------
// x -> catx -> (hi, lo) bf16. One thread = 4 consecutive elements. D must be pow2 (2048).
__global__ __launch_bounds__(256) void transform_x(
    const float* __restrict__ x, const float* __restrict__ scale, const float* __restrict__ shift,
    unsigned short* __restrict__ Ahi, unsigned short* __restrict__ Alo, int D)
{
    size_t base = ((size_t)blockIdx.x * 256 + threadIdx.x) * 4;
    float4v v = *(const float4v*)(x + base);
    int k = (int)(base & (size_t)(D - 1));
    ushort4v h, l;
    #pragma unroll
    for (int j = 0; j < 4; ++j) {
        float c = fmaf(v[j], scale[k + j], shift[k + j]);
        unsigned short hb = f2bf(c);
        h[j] = hb;
        l[j] = f2bf(c - bfbits2f(hb));
    }
    *(ushort4v*)(Ahi + base) = h;
    *(ushort4v*)(Alo + base) = l;
}

// w -> (hi, lo) bf16
__global__ __launch_bounds__(256) void transform_w(
    const float* __restrict__ w, unsigned short* __restrict__ Whi, unsigned short* __restrict__ Wlo)
{
    size_t base = ((size_t)blockIdx.x * 256 + threadIdx.x) * 4;
    float4v v = *(const float4v*)(w + base);
    ushort4v h, l;
    #pragma unroll
    for (int j = 0; j < 4; ++j) {
        unsigned short hb = f2bf(v[j]);
        h[j] = hb;
        l[j] = f2bf(v[j] - bfbits2f(hb));
    }
    *(ushort4v*)(Whi + base) = h;
    *(ushort4v*)(Wlo + base) = l;
}

// ---------------- bf16x3 fused dual GEMM ----------------
// Block tile 128(M) x 64(N), BK=32. 256 threads = 4 waves (2x2), wave tile 64x32.
// Per wave per K-step: 48 MFMA (3 products x 2 gemms x 4mt x 2nt).
// LDS: 6 tiles x [rows][32] bf16, seg-swizzled: phys_seg = seg ^ ((row>>1)&3).
// Staged via global_load_lds w=16 with pre-swizzled per-lane GLOBAL source (rule #21:
// linear LDS dest + inverse-swizzled source + swizzled ds_read).
__global__ __launch_bounds__(256) void dual_gemm_bf16x3(
    const unsigned short* __restrict__ Ahi, const unsigned short* __restrict__ Alo,
    const unsigned short* __restrict__ B1h, const unsigned short* __restrict__ B1l,
    const unsigned short* __restrict__ B2h, const unsigned short* __restrict__ B2l,
    const float* __restrict__ b1, const float* __restrict__ b2,
    float* __restrict__ out, int N, int D, int O)
{
    __shared__ unsigned short sm[16384];  // 32 KB
    constexpr int oAh = 0, oAl = 4096, o1h = 8192, o1l = 10240, o2h = 12288, o2l = 14336;

    const int t = threadIdx.x;
    const int lane = t & 63;
    const int wid = t >> 6;
    const int wm = wid >> 1, wn = wid & 1;
    const int bm = blockIdx.x * 128;
    const int bn = blockIdx.y * 64;

    // staging: slot s -> row = s>>2, phys seg = s&3, logical seg = phys ^ ((row>>1)&3)
    const int r0 = t >> 2;         // 0..63
    const int sp = t & 3;
    const int r1 = r0 + 64;        // A tile second half
    const int sl0 = sp ^ ((r0 >> 1) & 3);
    const int sl1 = sp ^ ((r1 >> 1) & 3);

    const unsigned short* gAh0 = Ahi + (size_t)(bm + r0) * D + sl0 * 8;
    const unsigned short* gAh1 = Ahi + (size_t)(bm + r1) * D + sl1 * 8;
    const unsigned short* gAl0 = Alo + (size_t)(bm + r0) * D + sl0 * 8;
    const unsigned short* gAl1 = Alo + (size_t)(bm + r1) * D + sl1 * 8;
    const unsigned short* g1h  = B1h + (size_t)(bn + r0) * D + sl0 * 8;
    const unsigned short* g1l  = B1l + (size_t)(bn + r0) * D + sl0 * 8;
    const unsigned short* g2h  = B2h + (size_t)(bn + r0) * D + sl0 * 8;
    const unsigned short* g2l  = B2l + (size_t)(bn + r0) * D + sl0 * 8;

    unsigned short* dA0 = &sm[oAh + t * 8];
    unsigned short* dA1 = &sm[oAh + (t + 256) * 8];
    unsigned short* dL0 = &sm[oAl + t * 8];
    unsigned short* dL1 = &sm[oAl + (t + 256) * 8];
    unsigned short* d1h = &sm[o1h + t * 8];
    unsigned short* d1l = &sm[o1l + t * 8];
    unsigned short* d2h = &sm[o2h + t * 8];
    unsigned short* d2l = &sm[o2l + t * 8];

    // fragment read offsets (elements within a tile); 16B-aligned -> ds_read_b128
    int aoff[4], boff[2];
    #pragma unroll
    for (int mt = 0; mt < 4; ++mt) {
        int row = wm * 64 + mt * 16 + (lane & 15);
        int seg = (lane >> 4) ^ ((row >> 1) & 3);
        aoff[mt] = row * 32 + seg * 8;
    }
    #pragma unroll
    for (int nt = 0; nt < 2; ++nt) {
        int row = wn * 32 + nt * 16 + (lane & 15);
        int seg = (lane >> 4) ^ ((row >> 1) & 3);
        boff[nt] = row * 32 + seg * 8;
    }

    f32x4 acc1[4][2], acc2[4][2];
    #pragma unroll
    for (int mt = 0; mt < 4; ++mt)
        #pragma unroll
        for (int nt = 0; nt < 2; ++nt) {
            acc1[mt][nt] = (f32x4){0.f, 0.f, 0.f, 0.f};
            acc2[mt][nt] = (f32x4){0.f, 0.f, 0.f, 0.f};
        }

    for (int k0 = 0; k0 < D; k0 += 32) {
        GL16(gAh0 + k0, dA0);  GL16(gAh1 + k0, dA1);
        GL16(gAl0 + k0, dL0);  GL16(gAl1 + k0, dL1);
        GL16(g1h + k0, d1h);   GL16(g1l + k0, d1l);
        GL16(g2h + k0, d2h);   GL16(g2l + k0, d2l);
        __syncthreads();  // compiler drains vmcnt(0) before s_barrier

        bf16x8 ah[4], al[4], bb0, bb1;
        #pragma unroll
        for (int mt = 0; mt < 4; ++mt) {
            ah[mt] = *(const bf16x8*)&sm[oAh + aoff[mt]];
            al[mt] = *(const bf16x8*)&sm[oAl + aoff[mt]];
        }

        // gemm1: Ahi*B1hi + Alo*B1hi + Ahi*B1lo
        bb0 = *(const bf16x8*)&sm[o1h + boff[0]];
        bb1 = *(const bf16x8*)&sm[o1h + boff[1]];
        #pragma unroll
        for (int mt = 0; mt < 4; ++mt) {
            acc1[mt][0] = MFMA(ah[mt], bb0, acc1[mt][0]);
            acc1[mt][1] = MFMA(ah[mt], bb1, acc1[mt][1]);
        }
        #pragma unroll
        for (int mt = 0; mt < 4; ++mt) {
            acc1[mt][0] = MFMA(al[mt], bb0, acc1[mt][0]);
            acc1[mt][1] = MFMA(al[mt], bb1, acc1[mt][1]);
        }
        bb0 = *(const bf16x8*)&sm[o1l + boff[0]];
        bb1 = *(const bf16x8*)&sm[o1l + boff[1]];
        #pragma unroll
        for (int mt = 0; mt < 4; ++mt) {
            acc1[mt][0] = MFMA(ah[mt], bb0, acc1[mt][0]);
            acc1[mt][1] = MFMA(ah[mt], bb1, acc1[mt][1]);
        }

        // gemm2: Ahi*B2hi + Alo*B2hi + Ahi*B2lo
        bb0 = *(const bf16x8*)&sm[o2h + boff[0]];
        bb1 = *(const bf16x8*)&sm[o2h + boff[1]];
        #pragma unroll
        for (int mt = 0; mt < 4; ++mt) {
            acc2[mt][0] = MFMA(ah[mt], bb0, acc2[mt][0]);
            acc2[mt][1] = MFMA(ah[mt], bb1, acc2[mt][1]);
        }
        #pragma unroll
        for (int mt = 0; mt < 4; ++mt) {
            acc2[mt][0] = MFMA(al[mt], bb0, acc2[mt][0]);
            acc2[mt][1] = MFMA(al[mt], bb1, acc2[mt][1]);
        }
        bb0 = *(const bf16x8*)&sm[o2l + boff[0]];
        bb1 = *(const bf16x8*)&sm[o2l + boff[1]];
        #pragma unroll
        for (int mt = 0; mt < 4; ++mt) {
            acc2[mt][0] = MFMA(ah[mt], bb0, acc2[mt][0]);
            acc2[mt][1] = MFMA(ah[mt], bb1, acc2[mt][1]);
        }
        __syncthreads();
    }

    // epilogue: C/D layout (verified m89): col = lane&15, row = (lane>>4)*4 + reg
    #pragma unroll
    for (int nt = 0; nt < 2; ++nt) {
        int col = bn + wn * 32 + nt * 16 + (lane & 15);
        float bia1 = b1[col], bia2 = b2[col];
        #pragma unroll
        for (int mt = 0; mt < 4; ++mt) {
            #pragma unroll
            for (int r = 0; r < 4; ++r) {
                int row = bm + wm * 64 + mt * 16 + (lane >> 4) * 4 + r;
                float h1 = acc1[mt][nt][r] + bia1;
                float h2 = acc2[mt][nt][r] + bia2;
                float sg = 1.0f / (1.0f + expf(-h2));
                out[(size_t)row * O + col] = clamp_small(h1) * clamp_small(sg);
            }
        }
    }
}

// ---------------- R1 fp32 fallback (known-correct) ----------------
constexpr int BM = 128, BN = 64, BK = 16;
constexpr int APAD = BM + 4;
constexpr int BPAD = BN + 4;

__global__ __launch_bounds__(256) void dual_gemm_f32(
    const float* __restrict__ x,
    const float* __restrict__ w1, const float* __restrict__ b1,
    const float* __restrict__ w2, const float* __restrict__ b2,
    const float* __restrict__ scale, const float* __restrict__ shift,
    float* __restrict__ out, int N, int D, int O)
{
    __shared__ float As [BK][APAD];
    __shared__ float Bs1[BK][BPAD];
    __shared__ float Bs2[BK][BPAD];

    const int tid = threadIdx.x;
    const int ty = tid >> 4;
    const int tx = tid & 15;
    const int bm = blockIdx.x * BM;
    const int bn = blockIdx.y * BN;

    float acc1[8][4] = {};
    float acc2[8][4] = {};

    for (int k0 = 0; k0 < D; k0 += BK) {
        #pragma unroll
        for (int i = 0; i < 8; ++i) {
            int e = tid + i * 256;
            int row = e >> 4;
            int kk = e & 15;
            float v = x[(size_t)(bm + row) * D + (k0 + kk)];
            As[kk][row] = fmaf(v, scale[k0 + kk], shift[k0 + kk]);
        }
        #pragma unroll
        for (int i = 0; i < 4; ++i) {
            int e = tid + i * 256;
            int o = e >> 4;
            int kk = e & 15;
            Bs1[kk][o] = w1[(size_t)(bn + o) * D + (k0 + kk)];
            Bs2[kk][o] = w2[(size_t)(bn + o) * D + (k0 + kk)];
        }
        __syncthreads();
        #pragma unroll
        for (int kk = 0; kk < BK; ++kk) {
            float a[8], v1[4], v2[4];
            #pragma unroll
            for (int i = 0; i < 8; ++i) a[i] = As[kk][ty * 8 + i];
            #pragma unroll
            for (int j = 0; j < 4; ++j) { v1[j] = Bs1[kk][tx * 4 + j]; v2[j] = Bs2[kk][tx * 4 + j]; }
            #pragma unroll
            for (int i = 0; i < 8; ++i)
                #pragma unroll
                for (int j = 0; j < 4; ++j) {
                    acc1[i][j] = fmaf(a[i], v1[j], acc1[i][j]);
                    acc2[i][j] = fmaf(a[i], v2[j], acc2[i][j]);
                }
        }
        __syncthreads();
    }

    float bias1[4], bias2[4];
    #pragma unroll
    for (int j = 0; j < 4; ++j) {
        bias1[j] = b1[bn + tx * 4 + j];
        bias2[j] = b2[bn + tx * 4 + j];
    }
    #pragma unroll
    for (int i = 0; i < 8; ++i) {
        #pragma unroll
        for (int j = 0; j < 4; ++j) {
            float h1 = acc1[i][j] + bias1[j];
            float h2 = acc2[i][j] + bias2[j];
            float sg = 1.0f / (1.0f + expf(-h2));
            out[(size_t)(bm + ty * 8 + i) * O + (bn + tx * 4 + j)] = clamp_small(h1) * clamp_small(sg);
        }
    }
}

extern "C" void kernel_launch(void* const* d_in, const int* in_sizes, int n_in,
                              void* d_out, int out_size, void* d_ws, size_t ws_size,
                              hipStream_t stream)
{
    const float* x     = (const float*)d_in[0];
    const float* w1    = (const float*)d_in[1];
    const float* b1    = (const float*)d_in[2];
    const float* w2    = (const float*)d_in[3];
    const float* b2    = (const float*)d_in[4];
    const float* gamma = (const float*)d_in[5];
    const float* beta  = (const float*)d_in[6];
    float* out = (float*)d_out;

    const int D = in_sizes[5];        // 2048
    const int O = in_sizes[2];        // 2048
    const int N = in_sizes[0] / D;    // 16384

    const int RB = 64;
    char* wp = (char*)d_ws;
    float* psum  = (float*)wp;                         wp += (size_t)RB * D * 4;
    float* psq   = (float*)wp;                         wp += (size_t)RB * D * 4;
    float* scale = (float*)wp;                         wp += (size_t)D * 4;
    float* shift = (float*)wp;                         wp += (size_t)D * 4;
    unsigned short* Ahi = (unsigned short*)wp;         wp += (size_t)N * D * 2;
    unsigned short* Alo = (unsigned short*)wp;         wp += (size_t)N * D * 2;
    unsigned short* W1h = (unsigned short*)wp;         wp += (size_t)O * D * 2;
    unsigned short* W1l = (unsigned short*)wp;         wp += (size_t)O * D * 2;
    unsigned short* W2h = (unsigned short*)wp;         wp += (size_t)O * D * 2;
    unsigned short* W2l = (unsigned short*)wp;         wp += (size_t)O * D * 2;
    size_t need = (size_t)(wp - (char*)d_ws);

    stats_partial<<<dim3(D / 256, RB), 256, 0, stream>>>(x, psum, psq, N, D, N / RB);
    stats_finalize<<<(D + 255) / 256, 256, 0, stream>>>(psum, psq, gamma, beta, scale, shift, D, RB, (float)N);

    if (ws_size >= need) {
        transform_x<<<(int)(((size_t)N * D / 4) / 256), 256, 0, stream>>>(x, scale, shift, Ahi, Alo, D);
        transform_w<<<(int)(((size_t)O * D / 4) / 256), 256, 0, stream>>>(w1, W1h, W1l);
        transform_w<<<(int)(((size_t)O * D / 4) / 256), 256, 0, stream>>>(w2, W2h, W2l);
        dual_gemm_bf16x3<<<dim3(N / 128, O / 64), 256, 0, stream>>>(
            Ahi, Alo, W1h, W1l, W2h, W2l, b1, b2, out, N, D, O);
    } else {
        dual_gemm_f32<<<dim3(N / BM, O / BN), 256, 0, stream>>>(
            x, w1, b1, w2, b2, scale, shift, out, N, D, O);
    }
}

// Round 3
// 1089.973 us; speedup vs baseline: 3.3763x; 1.1103x over previous
//
#include <hip/hip_runtime.h>
#include <hip/hip_bf16.h>
#include <math.h>

// R3: bf16x3 dual-GEMM with m201-style phased schedule (counted vmcnt, never 0),
// 128x128 tile BK=32, 512 threads / 8 waves, dbuf 2x48KB LDS, setprio around MFMA,
// bn-fast + XCD-bijective block swizzle. Numerics identical to R2 (absmax-proven).

#define BN_EPS 1e-8f
#define CLAMP_EPS 1e-12f

typedef __attribute__((ext_vector_type(8))) __bf16 bf16x8;
typedef __attribute__((ext_vector_type(4))) float f32x4;
typedef __attribute__((ext_vector_type(4))) float float4v;
typedef __attribute__((ext_vector_type(8))) unsigned short ushort8v;
typedef unsigned short us;

__device__ __forceinline__ float clamp_small(float t) {
    if (t >= 0.0f && t < CLAMP_EPS) t = CLAMP_EPS;
    else if (t < 0.0f && t > -CLAMP_EPS) t = -CLAMP_EPS;
    return t;
}
__device__ __forceinline__ us f2bf(float v) {
    __hip_bfloat16 b = __float2bfloat16(v);  // RNE
    return __builtin_bit_cast(us, b);
}
__device__ __forceinline__ float bfbits2f(us u) {
    unsigned int x = ((unsigned int)u) << 16;
    return __builtin_bit_cast(float, x);
}

#define GL16(g, l)                                                              \
    __builtin_amdgcn_global_load_lds(                                           \
        (const __attribute__((address_space(1))) void*)(g),                     \
        (__attribute__((address_space(3))) void*)(l), 16, 0, 0)
#define MFMA(a, b, c) __builtin_amdgcn_mfma_f32_16x16x32_bf16((a), (b), (c), 0, 0, 0)
#define WAITV(n) asm volatile("s_waitcnt vmcnt(" #n ")" ::: "memory")
#define WAITL0   asm volatile("s_waitcnt lgkmcnt(0)" ::: "memory")
#define BAR()    do { asm volatile("" ::: "memory"); __builtin_amdgcn_s_barrier(); \
                      asm volatile("" ::: "memory"); } while (0)

// ---------------- stats ----------------
__global__ __launch_bounds__(256) void stats_partial(
    const float* __restrict__ x, float* __restrict__ psum, float* __restrict__ psq,
    int N, int D, int rows_per_block)
{
    int col = blockIdx.x * 256 + threadIdx.x;
    int r0 = blockIdx.y * rows_per_block;
    const float* p = x + (size_t)r0 * D + col;
    float s = 0.0f, q = 0.0f;
    for (int r = 0; r < rows_per_block; ++r) {
        float v = p[(size_t)r * D];
        s += v;
        q += v * v;
    }
    psum[(size_t)blockIdx.y * D + col] = s;
    psq [(size_t)blockIdx.y * D + col] = q;
}

__global__ __launch_bounds__(256) void stats_finalize(
    const float* __restrict__ psum, const float* __restrict__ psq,
    const float* __restrict__ gamma, const float* __restrict__ beta,
    float* __restrict__ scale, float* __restrict__ shift,
    int D, int nparts, float n)
{
    int col = blockIdx.x * 256 + threadIdx.x;
    if (col >= D) return;
    float s = 0.0f, q = 0.0f;
    for (int i = 0; i < nparts; ++i) {
        s += psum[(size_t)i * D + col];
        q += psq [(size_t)i * D + col];
    }
    float mean = s / n;
    float var = (q - n * mean * mean) / (n - 1.0f);  // ddof=1
    float vs = rsqrtf(var + BN_EPS);
    float sc = gamma[col] * vs;
    scale[col] = sc;
    shift[col] = beta[col] - mean * sc;
}

// ---------------- split transforms (8 elem/thread, 16B stores) ----------------
__global__ __launch_bounds__(256) void transform_x8(
    const float* __restrict__ x, const float* __restrict__ scale, const float* __restrict__ shift,
    us* __restrict__ Ahi, us* __restrict__ Alo, int D)
{
    size_t base = ((size_t)blockIdx.x * 256 + threadIdx.x) * 8;
    int k = (int)(base & (size_t)(D - 1));
    float4v v0 = *(const float4v*)(x + base);
    float4v v1 = *(const float4v*)(x + base + 4);
    float4v sc0 = *(const float4v*)(scale + k);
    float4v sc1 = *(const float4v*)(scale + k + 4);
    float4v sh0 = *(const float4v*)(shift + k);
    float4v sh1 = *(const float4v*)(shift + k + 4);
    ushort8v h, l;
    #pragma unroll
    for (int j = 0; j < 4; ++j) {
        float c = fmaf(v0[j], sc0[j], sh0[j]);
        us hb = f2bf(c); h[j] = hb; l[j] = f2bf(c - bfbits2f(hb));
    }
    #pragma unroll
    for (int j = 0; j < 4; ++j) {
        float c = fmaf(v1[j], sc1[j], sh1[j]);
        us hb = f2bf(c); h[4 + j] = hb; l[4 + j] = f2bf(c - bfbits2f(hb));
    }
    *(ushort8v*)(Ahi + base) = h;
    *(ushort8v*)(Alo + base) = l;
}

__global__ __launch_bounds__(256) void transform_w8(
    const float* __restrict__ w1, const float* __restrict__ w2,
    us* __restrict__ W1h, us* __restrict__ W1l,
    us* __restrict__ W2h, us* __restrict__ W2l)
{
    const float* w = blockIdx.y ? w2 : w1;
    us* wh = blockIdx.y ? W2h : W1h;
    us* wl = blockIdx.y ? W2l : W1l;
    size_t base = ((size_t)blockIdx.x * 256 + threadIdx.x) * 8;
    float4v v0 = *(const float4v*)(w + base);
    float4v v1 = *(const float4v*)(w + base + 4);
    ushort8v h, l;
    #pragma unroll
    for (int j = 0; j < 4; ++j) {
        us hb = f2bf(v0[j]); h[j] = hb; l[j] = f2bf(v0[j] - bfbits2f(hb));
    }
    #pragma unroll
    for (int j = 0; j < 4; ++j) {
        us hb = f2bf(v1[j]); h[4 + j] = hb; l[4 + j] = f2bf(v1[j] - bfbits2f(hb));
    }
    *(ushort8v*)(wh + base) = h;
    *(ushort8v*)(wl + base) = l;
}

// ---------------- phased dual GEMM ----------------
// Streams per K-tile(32): Ahi(8KB) Alo W1h W1l W2h W2l, each 1 global_load_lds of 8KB.
// LDS sub-tile layout [row][4 segs x 8 bf16], phys seg = logical seg ^ ((row>>1)&3)
// (2-way bank alias only = free; measured 0 conflicts in R2).
// Issue order per tile: l1=Ahi l2=W1h l3=W1l l4=Alo l5=W2h l6=W2l (issued during tile t-1).
// Phase needs: ph1 {l1,l2,l3}, ph2 {l4,l5}, ph3 {l6}.
// Counted waits: end-ph1 vmcnt(3), end-ph2 vmcnt(4), end-ph3 vmcnt(3). Never 0.
constexpr int TM = 128, TN = 128, TK = 32;
constexpr int BUFE = 24576;  // elems per buffer (48KB)
constexpr int oAh = 0, oAl = 4096, o1h = 8192, o1l = 12288, o2h = 16384, o2l = 20480;

#define TILE_BODY(C, X, ti)                                                         \
  {                                                                                 \
    const int kp = (((ti) < NT - 1) ? ((ti) + 1) : (ti)) * TK;                      \
    bf16x8 ah[4], al[4], w1h[2], w1l[2], w2h[2], w2l[2];                            \
    /* ---- phase 1: needs Ahi,W1h,W1l ---- */                                      \
    _Pragma("unroll")                                                               \
    for (int m = 0; m < 4; ++m) ah[m] = *(const bf16x8*)(sm + (C) + oAh + abase + m * 512); \
    _Pragma("unroll")                                                               \
    for (int n = 0; n < 2; ++n) {                                                   \
        w1h[n] = *(const bf16x8*)(sm + (C) + o1h + wbase + n * 512);                \
        w1l[n] = *(const bf16x8*)(sm + (C) + o1l + wbase + n * 512);                \
    }                                                                               \
    GL16(Ahi + ga + kp, sm + (X) + oAh + t * 8);                                    \
    GL16(W1h + gw + kp, sm + (X) + o1h + t * 8);                                    \
    BAR(); WAITL0;                                                                  \
    __builtin_amdgcn_s_setprio(1);                                                  \
    _Pragma("unroll")                                                               \
    for (int m = 0; m < 4; ++m) { _Pragma("unroll")                                 \
        for (int n = 0; n < 2; ++n) acc1[m][n] = MFMA(ah[m], w1h[n], acc1[m][n]); } \
    _Pragma("unroll")                                                               \
    for (int m = 0; m < 4; ++m) { _Pragma("unroll")                                 \
        for (int n = 0; n < 2; ++n) acc1[m][n] = MFMA(ah[m], w1l[n], acc1[m][n]); } \
    __builtin_amdgcn_s_setprio(0);                                                  \
    WAITV(3); BAR();                                                                \
    /* ---- phase 2: needs Alo,W2h ---- */                                          \
    _Pragma("unroll")                                                               \
    for (int m = 0; m < 4; ++m) al[m] = *(const bf16x8*)(sm + (C) + oAl + abase + m * 512); \
    _Pragma("unroll")                                                               \
    for (int n = 0; n < 2; ++n) w2h[n] = *(const bf16x8*)(sm + (C) + o2h + wbase + n * 512); \
    GL16(W1l + gw + kp, sm + (X) + o1l + t * 8);                                    \
    GL16(Alo + ga + kp, sm + (X) + oAl + t * 8);                                    \
    BAR(); WAITL0;                                                                  \
    __builtin_amdgcn_s_setprio(1);                                                  \
    _Pragma("unroll")                                                               \
    for (int m = 0; m < 4; ++m) { _Pragma("unroll")                                 \
        for (int n = 0; n < 2; ++n) acc1[m][n] = MFMA(al[m], w1h[n], acc1[m][n]); } \
    _Pragma("unroll")                                                               \
    for (int m = 0; m < 4; ++m) { _Pragma("unroll")                                 \
        for (int n = 0; n < 2; ++n) acc2[m][n] = MFMA(ah[m], w2h[n], acc2[m][n]); } \
    __builtin_amdgcn_s_setprio(0);                                                  \
    WAITV(4); BAR();                                                                \
    /* ---- phase 3: needs W2l ---- */                                              \
    _Pragma("unroll")                                                               \
    for (int n = 0; n < 2; ++n) w2l[n] = *(const bf16x8*)(sm + (C) + o2l + wbase + n * 512); \
    GL16(W2h + gw + kp, sm + (X) + o2h + t * 8);                                    \
    GL16(W2l + gw + kp, sm + (X) + o2l + t * 8);                                    \
    BAR(); WAITL0;                                                                  \
    __builtin_amdgcn_s_setprio(1);                                                  \
    _Pragma("unroll")                                                               \
    for (int m = 0; m < 4; ++m) { _Pragma("unroll")                                 \
        for (int n = 0; n < 2; ++n) acc2[m][n] = MFMA(al[m], w2h[n], acc2[m][n]); } \
    _Pragma("unroll")                                                               \
    for (int m = 0; m < 4; ++m) { _Pragma("unroll")                                 \
        for (int n = 0; n < 2; ++n) acc2[m][n] = MFMA(ah[m], w2l[n], acc2[m][n]); } \
    __builtin_amdgcn_s_setprio(0);                                                  \
    WAITV(3); BAR();                                                                \
  }

__global__ __launch_bounds__(512, 2) void dual_gemm_ph(
    const us* __restrict__ Ahi, const us* __restrict__ Alo,
    const us* __restrict__ W1h, const us* __restrict__ W1l,
    const us* __restrict__ W2h, const us* __restrict__ W2l,
    const float* __restrict__ b1, const float* __restrict__ b2,
    float* __restrict__ out, int N, int D, int O)
{
    __shared__ us sm[2 * BUFE];  // 96KB

    const int t = threadIdx.x;
    const int lane = t & 63;
    const int wid = t >> 6;
    const int wm = wid >> 2, wn = wid & 3;   // 2M x 4N wave grid, wave tile 64x32

    // bn-fast + XCD swizzle (grid 2048 = 8 * 256, bijective)
    const int nbn = O / TN;                   // 16
    const int b = blockIdx.x;
    const int lb = (b & 7) * ((int)gridDim.x >> 3) + (b >> 3);
    const int bm = (lb / nbn) * TM;
    const int bn = (lb % nbn) * TN;

    // staging addresses: dest slot t -> row t>>2, phys seg t&3; source uses logical seg
    const int srow = t >> 2, sp = t & 3;
    const int slseg = sp ^ ((srow >> 1) & 3);
    const size_t ga = (size_t)(bm + srow) * D + slseg * 8;
    const size_t gw = (size_t)(bn + srow) * D + slseg * 8;

    // fragment read bases: phys seg same for all frags of this lane (16-row strides)
    const int r15 = lane & 15;
    const int p = (lane >> 4) ^ ((r15 >> 1) & 3);
    const int abase = (wm * 64 + r15) * 32 + p * 8;
    const int wbase = (wn * 32 + r15) * 32 + p * 8;

    f32x4 acc1[4][2], acc2[4][2];
    #pragma unroll
    for (int m = 0; m < 4; ++m)
        #pragma unroll
        for (int n = 0; n < 2; ++n) {
            acc1[m][n] = (f32x4){0.f, 0.f, 0.f, 0.f};
            acc2[m][n] = (f32x4){0.f, 0.f, 0.f, 0.f};
        }

    const int NT = D / TK;  // 64

    // prologue: stage tile 0 into buffer 0, issue order l1..l6
    GL16(Ahi + ga, sm + oAh + t * 8);
    GL16(W1h + gw, sm + o1h + t * 8);
    GL16(W1l + gw, sm + o1l + t * 8);
    GL16(Alo + ga, sm + oAl + t * 8);
    GL16(W2h + gw, sm + o2h + t * 8);
    GL16(W2l + gw, sm + o2l + t * 8);
    WAITV(3);
    BAR();

    #pragma unroll 1
    for (int tt = 0; tt < NT; tt += 2) {
        TILE_BODY(0, BUFE, tt);
        TILE_BODY(BUFE, 0, tt + 1);
    }

    WAITV(0);  // drain dummy tail prefetch before LDS goes out of scope

    // epilogue: C/D mapping col=lane&15, row=(lane>>4)*4+reg (verified R2)
    #pragma unroll
    for (int n = 0; n < 2; ++n) {
        int col = bn + wn * 32 + n * 16 + r15;
        float bb1 = b1[col], bb2 = b2[col];
        #pragma unroll
        for (int m = 0; m < 4; ++m) {
            #pragma unroll
            for (int r = 0; r < 4; ++r) {
                int row = bm + wm * 64 + m * 16 + (lane >> 4) * 4 + r;
                float h1 = acc1[m][n][r] + bb1;
                float h2 = acc2[m][n][r] + bb2;
                float sg = 1.0f / (1.0f + expf(-h2));
                out[(size_t)row * O + col] = clamp_small(h1) * clamp_small(sg);
            }
        }
    }
}

extern "C" void kernel_launch(void* const* d_in, const int* in_sizes, int n_in,
                              void* d_out, int out_size, void* d_ws, size_t ws_size,
                              hipStream_t stream)
{
    const float* x     = (const float*)d_in[0];
    const float* w1    = (const float*)d_in[1];
    const float* b1    = (const float*)d_in[2];
    const float* w2    = (const float*)d_in[3];
    const float* b2    = (const float*)d_in[4];
    const float* gamma = (const float*)d_in[5];
    const float* beta  = (const float*)d_in[6];
    float* out = (float*)d_out;

    const int D = in_sizes[5];        // 2048
    const int O = in_sizes[2];        // 2048
    const int N = in_sizes[0] / D;    // 16384

    const int RB = 64;
    char* wp = (char*)d_ws;
    float* psum  = (float*)wp;                 wp += (size_t)RB * D * 4;
    float* psq   = (float*)wp;                 wp += (size_t)RB * D * 4;
    float* scale = (float*)wp;                 wp += (size_t)D * 4;
    float* shift = (float*)wp;                 wp += (size_t)D * 4;
    us* Ahi = (us*)wp;                         wp += (size_t)N * D * 2;
    us* Alo = (us*)wp;                         wp += (size_t)N * D * 2;
    us* W1h = (us*)wp;                         wp += (size_t)O * D * 2;
    us* W1l = (us*)wp;                         wp += (size_t)O * D * 2;
    us* W2h = (us*)wp;                         wp += (size_t)O * D * 2;
    us* W2l = (us*)wp;                         wp += (size_t)O * D * 2;

    stats_partial<<<dim3(D / 256, RB), 256, 0, stream>>>(x, psum, psq, N, D, N / RB);
    stats_finalize<<<(D + 255) / 256, 256, 0, stream>>>(psum, psq, gamma, beta, scale, shift, D, RB, (float)N);
    transform_x8<<<(int)(((size_t)N * D / 8) / 256), 256, 0, stream>>>(x, scale, shift, Ahi, Alo, D);
    transform_w8<<<dim3((int)(((size_t)O * D / 8) / 256), 2), 256, 0, stream>>>(w1, w2, W1h, W1l, W2h, W2l);
    dual_gemm_ph<<<(N / TM) * (O / TN), 512, 0, stream>>>(
        Ahi, Alo, W1h, W1l, W2h, W2l, b1, b2, out, N, D, O);
}